// Round 10
// baseline (614.478 us; speedup 1.0000x reference)
//
#include <hip/hip_runtime.h>
#include <hip/hip_bf16.h>

#define DIN 128
#define DH  128
#define DOUT 64

// bucketed CSR build: 512 nodes per bucket (dst >> 9), N=100000 -> 196 buckets
#define BSHIFT 9
#define BNODES 512
#define BCAP   12288      // capacity per bucket (mean 8163, sigma ~90 -> 45 sigma margin)
#define CHUNK  2048       // edges per bin_scatter workgroup (8 per thread, ~3 blocks/CU)

typedef __attribute__((ext_vector_type(8))) short short8;
typedef __attribute__((ext_vector_type(4))) float f32x4;

static __device__ __forceinline__ unsigned short f2bf(float f) {
    unsigned int u = __float_as_uint(f);
    u += 0x7FFFu + ((u >> 16) & 1u);   // RNE
    return (unsigned short)(u >> 16);
}
static __device__ __forceinline__ float bflo(unsigned int p) {
    return __uint_as_float(p << 16);
}
static __device__ __forceinline__ float bfhi(unsigned int p) {
    return __uint_as_float(p & 0xFFFF0000u);
}

// ---------------- weights: transpose + cast to bf16 (also zeroes bucket cursors) ----
__global__ __launch_bounds__(256) void prep_w_kernel(const float* __restrict__ W1,
                                                     const float* __restrict__ W2,
                                                     const float* __restrict__ W3,
                                                     unsigned short* __restrict__ Wt1,
                                                     unsigned short* __restrict__ Wt2,
                                                     unsigned short* __restrict__ Wt3,
                                                     int* __restrict__ gcur) {
    int i = blockIdx.x * 256 + threadIdx.x;
    if (blockIdx.x == 0) gcur[threadIdx.x] = 0;
    if (i < 128 * 128) {
        int n = i >> 7, k = i & 127;
        Wt1[n * 128 + k] = f2bf(W1[k * 128 + n]);
        Wt2[n * 128 + k] = f2bf(W2[k * 128 + n]);
        if (n < 64) Wt3[n * 128 + k] = f2bf(W3[k * 64 + n]);
    }
}

// ---------------- pass A: multisplit edges into dst-buckets ----------------
// entry = (dst_local << 17) | src   (src < 2^17, dst_local < 512)
__global__ __launch_bounds__(256) void bin_scatter_kernel(const int* __restrict__ ei, int E,
                                                          int* __restrict__ gcur,
                                                          int* __restrict__ pairs) {
    __shared__ int hist[256];
    __shared__ int base[256];
    int t = threadIdx.x;
    hist[t] = 0;
    __syncthreads();
    int e0 = blockIdx.x * CHUNK;
    int srcs[8], dsts[8], rk[8];
    #pragma unroll
    for (int j = 0; j < 8; j++) {
        int e = e0 + j * 256 + t;
        if (e < E) {
            srcs[j] = ei[e];
            dsts[j] = ei[E + e];
            rk[j] = atomicAdd(&hist[dsts[j] >> BSHIFT], 1);
        } else {
            rk[j] = -1;
        }
    }
    __syncthreads();
    base[t] = (hist[t] > 0) ? atomicAdd(&gcur[t], hist[t]) : 0;
    __syncthreads();
    #pragma unroll
    for (int j = 0; j < 8; j++) {
        if (rk[j] >= 0) {
            int b = dsts[j] >> BSHIFT;
            int dl = dsts[j] & (BNODES - 1);
            pairs[(size_t)b * BCAP + base[b] + rk[j]] = (dl << 17) | srcs[j];
        }
    }
}

// ---------------- tiny scan: bucket edge counts (+self loops) -> bucket_base -------
__global__ __launch_bounds__(256) void scan_buckets_kernel(const int* __restrict__ gcur,
                                                           int* __restrict__ bucket_base,
                                                           int nbuck, int n) {
    __shared__ int s[256];
    int t = threadIdx.x;
    int own = 0;
    if (t < nbuck) {
        int lo = t << BSHIFT;
        int cnt = n - lo;
        if (cnt > BNODES) cnt = BNODES;
        if (cnt < 0) cnt = 0;
        own = gcur[t] + cnt;               // edges + self-loops in this bucket
    }
    s[t] = own;
    __syncthreads();
    for (int off = 1; off < 256; off <<= 1) {
        int v = (t >= off) ? s[t - off] : 0;
        __syncthreads();
        s[t] += v;
        __syncthreads();
    }
    if (t < nbuck) bucket_base[t] = s[t] - own;   // exclusive
}

// ---------------- merged pass B+C: per-bucket deg-count, local scan, CSR fill ------
// One 1024-thread block per bucket. pairs re-read in pass 2 is L2-hot (33 KB).
__global__ __launch_bounds__(1024) void bucket_build_kernel(const int* __restrict__ pairs,
                                                            const int* __restrict__ gcur,
                                                            const int* __restrict__ bucket_base,
                                                            int* __restrict__ row_start,
                                                            float* __restrict__ dis,
                                                            int* __restrict__ csr_src, int n) {
    __shared__ int cnt[BNODES];     // counts, then cursors
    __shared__ int snode[BNODES];   // inclusive degree scan
    int t = threadIdx.x, b = blockIdx.x;
    if (t < BNODES) cnt[t] = 0;
    __syncthreads();
    int m = gcur[b];
    const int* p = pairs + (size_t)b * BCAP;
    // pass 1: node degree counts
    for (int i = t; i < m; i += 1024) {
        atomicAdd(&cnt[p[i] >> 17], 1);
    }
    __syncthreads();
    // local inclusive scan over deg (= cnt + 1 self-loop for valid nodes)
    if (t < BNODES) {
        int node = (b << BSHIFT) + t;
        snode[t] = (node < n) ? cnt[t] + 1 : 0;
    }
    __syncthreads();
    for (int off = 1; off < BNODES; off <<= 1) {
        int v = (t < BNODES && t >= off) ? snode[t - off] : 0;
        __syncthreads();
        if (t < BNODES) snode[t] += v;
        __syncthreads();
    }
    int bbase = bucket_base[b];
    if (t < BNODES) {
        int node = (b << BSHIFT) + t;
        if (node < n) {
            int deg = cnt[t] + 1;
            int ex = bbase + snode[t] - deg;    // exclusive position
            row_start[node] = ex;
            dis[node] = rsqrtf((float)deg);
            csr_src[ex] = node;                 // self-loop entry
            cnt[t] = ex + 1;                    // cursor
            if (node == n - 1) row_start[n] = ex + deg;
        }
    }
    __syncthreads();
    // pass 2: fill CSR via LDS cursors (pairs now L2-hot)
    for (int i = t; i < m; i += 1024) {
        int pk = p[i];
        int pos = atomicAdd(&cnt[pk >> 17], 1);
        csr_src[pos] = pk & 0x1FFFF;
    }
}

// ---------------- bf16 MFMA GEMM, slice-major I/O ----------
// H output is SLICE-MAJOR: H[s][row][16] for s = col/16 (16-feature slices).
// AFP32: A is fp32 row-major (layer 1 reads x directly); else A is slice-major bf16.
template <int NOUT, bool AFP32>
__global__ __launch_bounds__(256) void gemm_bf16_kernel(const void* __restrict__ Av,
                                                        const unsigned short* __restrict__ Wt,
                                                        const float* __restrict__ dis,
                                                        unsigned short* __restrict__ H, int M) {
    int wave = (blockIdx.x * 256 + threadIdx.x) >> 6;
    int lane = threadIdx.x & 63;
    int m0 = wave << 4;
    if (m0 >= M) return;                  // M divisible by 16
    int m = lane & 15, q = lane >> 4;
    constexpr int NT = NOUT / 16;
    f32x4 acc[NT];
    #pragma unroll
    for (int t = 0; t < NT; t++) acc[t] = (f32x4){0.f, 0.f, 0.f, 0.f};
    const float* Arow32 = (const float*)Av + (size_t)(m0 + m) * 128;
    const unsigned short* Xs = (const unsigned short*)Av;
    #pragma unroll
    for (int kk = 0; kk < 4; kk++) {
        short8 a;
        if (AFP32) {
            float4 u = *(const float4*)(Arow32 + kk * 32 + q * 8);
            float4 v = *(const float4*)(Arow32 + kk * 32 + q * 8 + 4);
            a[0] = (short)f2bf(u.x); a[1] = (short)f2bf(u.y);
            a[2] = (short)f2bf(u.z); a[3] = (short)f2bf(u.w);
            a[4] = (short)f2bf(v.x); a[5] = (short)f2bf(v.y);
            a[6] = (short)f2bf(v.z); a[7] = (short)f2bf(v.w);
        } else {
            // A[row][kk*32+q*8 .. +7] lives in slice sl = 2kk + q/2, offset (q&1)*8
            int sl = 2 * kk + (q >> 1);
            a = *(const short8*)(Xs + ((size_t)sl * M + (m0 + m)) * 16 + (q & 1) * 8);
        }
        #pragma unroll
        for (int t = 0; t < NT; t++) {
            const short8* Bp = (const short8*)(Wt + (size_t)(t * 16 + m) * 128);
            short8 b = Bp[kk * 4 + q];    // W[kk*32+q*8+j][t*16+m]
            acc[t] = __builtin_amdgcn_mfma_f32_16x16x32_bf16(a, b, acc[t], 0, 0, 0);
        }
    }
    float ds[4];
    #pragma unroll
    for (int r = 0; r < 4; r++) ds[r] = dis[m0 + q * 4 + r];
    #pragma unroll
    for (int t = 0; t < NT; t++)
        #pragma unroll
        for (int r = 0; r < 4; r++)
            H[((size_t)t * M + (m0 + q * 4 + r)) * 16 + m] = f2bf(acc[t][r] * ds[r]);
}

// ---------------- XCD-pinned sliced CSR aggregation ----------
// H is slice-major [NSLICE][n][16] (16-feature bf16 slices, 32 B rows).
// Grid = NSLICE * chunks; slice = blockIdx.x % NSLICE -> with round-robin
// block->XCD dispatch each XCD gathers from ONE 3.2 MB slice (L2-resident).
// 4 lanes per row (8 B each), 64 rows per 256-thread block, 8-deep batches.
// csr_src read non-temporally to avoid polluting the hot slice in L2.
template <int NSLICE, bool RELU, bool OUTBF>
__global__ __launch_bounds__(256) void agg_slice_kernel(const unsigned short* __restrict__ H,
                                                        const int* __restrict__ row_start,
                                                        const int* __restrict__ csr_src,
                                                        const float* __restrict__ dis,
                                                        const float* __restrict__ bias,
                                                        void* __restrict__ out, int n) {
    int s = blockIdx.x % NSLICE;
    int chunk = blockIdx.x / NSLICE;
    int t = threadIdx.x;
    int row = chunk * 64 + (t >> 2);
    int l = t & 3;
    if (row >= n) return;
    const unsigned short* Hs = H + (size_t)s * n * 16;
    int c = l * 4;                       // 4 bf16 features per lane
    float a0 = 0.f, a1 = 0.f, a2 = 0.f, a3 = 0.f;
    int p0 = row_start[row], p1 = row_start[row + 1];
    int p = p0;
    for (; p + 8 <= p1; p += 8) {
        int e[8];
        #pragma unroll
        for (int u = 0; u < 8; u++) e[u] = __builtin_nontemporal_load(&csr_src[p + u]);
        uint2 h[8];
        #pragma unroll
        for (int u = 0; u < 8; u++) h[u] = *(const uint2*)(Hs + (size_t)e[u] * 16 + c);
        #pragma unroll
        for (int u = 0; u < 8; u++) {
            a0 += bflo(h[u].x); a1 += bfhi(h[u].x);
            a2 += bflo(h[u].y); a3 += bfhi(h[u].y);
        }
    }
    for (; p + 4 <= p1; p += 4) {
        int e0 = __builtin_nontemporal_load(&csr_src[p]);
        int e1 = __builtin_nontemporal_load(&csr_src[p + 1]);
        int e2 = __builtin_nontemporal_load(&csr_src[p + 2]);
        int e3 = __builtin_nontemporal_load(&csr_src[p + 3]);
        uint2 h0 = *(const uint2*)(Hs + (size_t)e0 * 16 + c);
        uint2 h1 = *(const uint2*)(Hs + (size_t)e1 * 16 + c);
        uint2 h2 = *(const uint2*)(Hs + (size_t)e2 * 16 + c);
        uint2 h3 = *(const uint2*)(Hs + (size_t)e3 * 16 + c);
        a0 += bflo(h0.x) + bflo(h1.x) + bflo(h2.x) + bflo(h3.x);
        a1 += bfhi(h0.x) + bfhi(h1.x) + bfhi(h2.x) + bfhi(h3.x);
        a2 += bflo(h0.y) + bflo(h1.y) + bflo(h2.y) + bflo(h3.y);
        a3 += bfhi(h0.y) + bfhi(h1.y) + bfhi(h2.y) + bfhi(h3.y);
    }
    for (; p < p1; p++) {
        int e = __builtin_nontemporal_load(&csr_src[p]);
        uint2 h = *(const uint2*)(Hs + (size_t)e * 16 + c);
        a0 += bflo(h.x); a1 += bfhi(h.x);
        a2 += bflo(h.y); a3 += bfhi(h.y);
    }
    float dd = dis[row];
    int bc = s * 16 + c;
    a0 = a0 * dd + bias[bc];
    a1 = a1 * dd + bias[bc + 1];
    a2 = a2 * dd + bias[bc + 2];
    a3 = a3 * dd + bias[bc + 3];
    if (RELU) {
        a0 = fmaxf(a0, 0.f); a1 = fmaxf(a1, 0.f);
        a2 = fmaxf(a2, 0.f); a3 = fmaxf(a3, 0.f);
    }
    if (OUTBF) {
        // slice-major bf16 output (feeds next GEMM)
        unsigned short* ob = (unsigned short*)out + (size_t)s * n * 16 + (size_t)row * 16 + c;
        uint2 pk;
        pk.x = ((unsigned int)f2bf(a1) << 16) | f2bf(a0);
        pk.y = ((unsigned int)f2bf(a3) << 16) | f2bf(a2);
        *(uint2*)ob = pk;
    } else {
        // row-major fp32 output (Z3 for decode)
        float* of = (float*)out + (size_t)row * (NSLICE * 16) + bc;
        *(float4*)of = make_float4(a0, a1, a2, a3);
    }
}

// ---------------- decode: hidden = z[a]*z[b]; logits = sum; normalize ----------------
// One 16-lane group per TWO pairs: 4 float4 gathers in flight per group.
__global__ __launch_bounds__(256) void decode_kernel(const float* __restrict__ Z,
                                                     const int* __restrict__ eli, int EL,
                                                     float* __restrict__ out_h,
                                                     float* __restrict__ out_l) {
    int g  = (blockIdx.x * 256 + threadIdx.x) >> 4;
    int gl = threadIdx.x & 15;
    int q0 = g * 2;
    if (q0 >= EL) return;
    int q1 = q0 + 1;
    bool has1 = q1 < EL;
    int a0 = eli[q0], b0 = eli[EL + q0];
    int a1 = has1 ? eli[q1] : a0;
    int b1 = has1 ? eli[EL + q1] : b0;
    float4 za0 = *(const float4*)(Z + (size_t)a0 * 64 + gl * 4);
    float4 zb0 = *(const float4*)(Z + (size_t)b0 * 64 + gl * 4);
    float4 za1 = *(const float4*)(Z + (size_t)a1 * 64 + gl * 4);
    float4 zb1 = *(const float4*)(Z + (size_t)b1 * 64 + gl * 4);

    float h00 = za0.x * zb0.x, h01 = za0.y * zb0.y, h02 = za0.z * zb0.z, h03 = za0.w * zb0.w;
    float h10 = za1.x * zb1.x, h11 = za1.y * zb1.y, h12 = za1.z * zb1.z, h13 = za1.w * zb1.w;
    float s0  = h00 + h01 + h02 + h03;
    float ss0 = h00 * h00 + h01 * h01 + h02 * h02 + h03 * h03;
    float s1  = h10 + h11 + h12 + h13;
    float ss1 = h10 * h10 + h11 * h11 + h12 * h12 + h13 * h13;
    #pragma unroll
    for (int off = 8; off > 0; off >>= 1) {
        s0  += __shfl_xor(s0, off, 64);
        ss0 += __shfl_xor(ss0, off, 64);
        s1  += __shfl_xor(s1, off, 64);
        ss1 += __shfl_xor(ss1, off, 64);
    }
    float inv0 = 1.0f / fmaxf(sqrtf(ss0), 1e-12f);
    *(float4*)(out_h + (size_t)q0 * 64 + gl * 4) =
        make_float4(h00 * inv0, h01 * inv0, h02 * inv0, h03 * inv0);
    if (gl == 0) out_l[q0] = s0;
    if (has1) {
        float inv1 = 1.0f / fmaxf(sqrtf(ss1), 1e-12f);
        *(float4*)(out_h + (size_t)q1 * 64 + gl * 4) =
            make_float4(h10 * inv1, h11 * inv1, h12 * inv1, h13 * inv1);
        if (gl == 0) out_l[q1] = s1;
    }
}

extern "C" void kernel_launch(void* const* d_in, const int* in_sizes, int n_in,
                              void* d_out, int out_size, void* d_ws, size_t ws_size,
                              hipStream_t stream) {
    const float* x  = (const float*)d_in[0];
    const float* W1 = (const float*)d_in[1];
    const float* b1 = (const float*)d_in[2];
    const float* W2 = (const float*)d_in[3];
    const float* b2 = (const float*)d_in[4];
    const float* W3 = (const float*)d_in[5];
    const float* b3 = (const float*)d_in[6];
    const int* edge_index = (const int*)d_in[7];
    const int* eli        = (const int*)d_in[8];

    const int N  = in_sizes[0] / DIN;
    const int E  = in_sizes[7] / 2;
    const int EL = in_sizes[8] / 2;
    const int NBUCK = (N + BNODES - 1) >> BSHIFT;   // 196 for N=100000 (<=256 required)

    char* w = (char*)d_ws;
    auto alloc = [&](size_t bytes) -> char* {
        char* p = w; w += (bytes + 255) & ~(size_t)255; return p;
    };
    unsigned short* bufA  = (unsigned short*)alloc((size_t)N * DH * 2);  // H1/H2/H3 (slice-major)
    unsigned short* bufB  = (unsigned short*)alloc((size_t)N * DH * 2);  // X1/X2 (slice-major)
    float*          Z3    = (float*)alloc((size_t)N * DOUT * 4);         // fp32 final embeddings
    unsigned short* Wt1   = (unsigned short*)alloc(128 * 128 * 2);
    unsigned short* Wt2   = (unsigned short*)alloc(128 * 128 * 2);
    unsigned short* Wt3   = (unsigned short*)alloc(64 * 128 * 2);
    int*            row_start = (int*)alloc((size_t)(N + 1) * 4);
    float*          dis    = (float*)alloc((size_t)N * 4);
    int*            gcur   = (int*)alloc(256 * 4);                       // bucket counts
    int*            bucket_base = (int*)alloc(256 * 4);                  // bucket CSR bases
    int*            csr_src = (int*)alloc((size_t)(E + N) * 4);
    int*            pairs  = (int*)alloc((size_t)NBUCK * BCAP * 4);      // bucketed edges

    float* out_h = (float*)d_out;
    float* out_l = out_h + (size_t)EL * DOUT;

    // --- build CSR (bucketed multisplit, consolidated) ---
    prep_w_kernel<<<64, 256, 0, stream>>>(W1, W2, W3, Wt1, Wt2, Wt3, gcur);
    bin_scatter_kernel<<<(E + CHUNK - 1) / CHUNK, 256, 0, stream>>>(edge_index, E, gcur, pairs);
    scan_buckets_kernel<<<1, 256, 0, stream>>>(gcur, bucket_base, NBUCK, N);
    bucket_build_kernel<<<NBUCK, 1024, 0, stream>>>(pairs, gcur, bucket_base,
                                                    row_start, dis, csr_src, N);

    const int gemm_grid = ((N / 16) * 64 + 255) / 256;
    const int chunks    = (N + 63) / 64;             // 64 rows per agg block

    // --- layer 1: GEMM (fp32 x -> H1 slice-major), sliced aggregate -> X1 ---
    gemm_bf16_kernel<128, true><<<gemm_grid, 256, 0, stream>>>(x, Wt1, dis, bufA, N);
    agg_slice_kernel<8, true, true><<<chunks * 8, 256, 0, stream>>>(bufA, row_start, csr_src, dis, b1, bufB, N);
    // --- layer 2 ---
    gemm_bf16_kernel<128, false><<<gemm_grid, 256, 0, stream>>>(bufB, Wt2, dis, bufA, N);
    agg_slice_kernel<8, true, true><<<chunks * 8, 256, 0, stream>>>(bufA, row_start, csr_src, dis, b2, bufB, N);
    // --- layer 3 ---
    gemm_bf16_kernel<64, false><<<gemm_grid, 256, 0, stream>>>(bufB, Wt3, dis, bufA, N);
    agg_slice_kernel<4, false, false><<<chunks * 4, 256, 0, stream>>>(bufA, row_start, csr_src, dis, b3, Z3, N);
    // --- decode ---
    const int dec_groups = (EL + 1) / 2;
    decode_kernel<<<(dec_groups * 16 + 255) / 256, 256, 0, stream>>>(Z3, eli, EL, out_h, out_l);
}

// Round 11
// 390.491 us; speedup vs baseline: 1.5736x; 1.5736x over previous
//
#include <hip/hip_runtime.h>
#include <hip/hip_bf16.h>

#define DIN 128
#define DH  128
#define DOUT 64

// bucketed CSR build: 512 nodes per bucket (dst >> 9), N=100000 -> 196 buckets
#define BSHIFT 9
#define BNODES 512
#define BCAP   12288      // capacity per bucket (mean 8163, sigma ~90 -> 45 sigma margin)
#define CHUNK  2048       // edges per bin_scatter workgroup (8 per thread, ~3 blocks/CU)

typedef __attribute__((ext_vector_type(8))) short short8;
typedef __attribute__((ext_vector_type(4))) float f32x4;

static __device__ __forceinline__ unsigned short f2bf(float f) {
    unsigned int u = __float_as_uint(f);
    u += 0x7FFFu + ((u >> 16) & 1u);   // RNE
    return (unsigned short)(u >> 16);
}
static __device__ __forceinline__ float bflo(unsigned int p) {
    return __uint_as_float(p << 16);
}
static __device__ __forceinline__ float bfhi(unsigned int p) {
    return __uint_as_float(p & 0xFFFF0000u);
}

// ---------------- weights: transpose + cast to bf16 (also zeroes bucket cursors) ----
__global__ __launch_bounds__(256) void prep_w_kernel(const float* __restrict__ W1,
                                                     const float* __restrict__ W2,
                                                     const float* __restrict__ W3,
                                                     unsigned short* __restrict__ Wt1,
                                                     unsigned short* __restrict__ Wt2,
                                                     unsigned short* __restrict__ Wt3,
                                                     int* __restrict__ gcur) {
    int i = blockIdx.x * 256 + threadIdx.x;
    if (blockIdx.x == 0) gcur[threadIdx.x] = 0;
    if (i < 128 * 128) {
        int n = i >> 7, k = i & 127;
        Wt1[n * 128 + k] = f2bf(W1[k * 128 + n]);
        Wt2[n * 128 + k] = f2bf(W2[k * 128 + n]);
        if (n < 64) Wt3[n * 128 + k] = f2bf(W3[k * 64 + n]);
    }
}

// ---------------- pass A: multisplit edges into dst-buckets ----------------
// entry = (dst_local << 17) | src   (src < 2^17, dst_local < 512)
__global__ __launch_bounds__(256) void bin_scatter_kernel(const int* __restrict__ ei, int E,
                                                          int* __restrict__ gcur,
                                                          int* __restrict__ pairs) {
    __shared__ int hist[256];
    __shared__ int base[256];
    int t = threadIdx.x;
    hist[t] = 0;
    __syncthreads();
    int e0 = blockIdx.x * CHUNK;
    int srcs[8], dsts[8], rk[8];
    #pragma unroll
    for (int j = 0; j < 8; j++) {
        int e = e0 + j * 256 + t;
        if (e < E) {
            srcs[j] = ei[e];
            dsts[j] = ei[E + e];
            rk[j] = atomicAdd(&hist[dsts[j] >> BSHIFT], 1);
        } else {
            rk[j] = -1;
        }
    }
    __syncthreads();
    base[t] = (hist[t] > 0) ? atomicAdd(&gcur[t], hist[t]) : 0;
    __syncthreads();
    #pragma unroll
    for (int j = 0; j < 8; j++) {
        if (rk[j] >= 0) {
            int b = dsts[j] >> BSHIFT;
            int dl = dsts[j] & (BNODES - 1);
            pairs[(size_t)b * BCAP + base[b] + rk[j]] = (dl << 17) | srcs[j];
        }
    }
}

// ---------------- tiny scan: bucket edge counts (+self loops) -> bucket_base -------
__global__ __launch_bounds__(256) void scan_buckets_kernel(const int* __restrict__ gcur,
                                                           int* __restrict__ bucket_base,
                                                           int nbuck, int n) {
    __shared__ int s[256];
    int t = threadIdx.x;
    int own = 0;
    if (t < nbuck) {
        int lo = t << BSHIFT;
        int cnt = n - lo;
        if (cnt > BNODES) cnt = BNODES;
        if (cnt < 0) cnt = 0;
        own = gcur[t] + cnt;               // edges + self-loops in this bucket
    }
    s[t] = own;
    __syncthreads();
    for (int off = 1; off < 256; off <<= 1) {
        int v = (t >= off) ? s[t - off] : 0;
        __syncthreads();
        s[t] += v;
        __syncthreads();
    }
    if (t < nbuck) bucket_base[t] = s[t] - own;   // exclusive
}

// ---------------- merged pass B+C: per-bucket deg-count, local scan, CSR fill ------
// One 1024-thread block per bucket. pairs re-read in pass 2 is L2-hot (33 KB).
__global__ __launch_bounds__(1024) void bucket_build_kernel(const int* __restrict__ pairs,
                                                            const int* __restrict__ gcur,
                                                            const int* __restrict__ bucket_base,
                                                            int* __restrict__ row_start,
                                                            float* __restrict__ dis,
                                                            int* __restrict__ csr_src, int n) {
    __shared__ int cnt[BNODES];     // counts, then cursors
    __shared__ int snode[BNODES];   // inclusive degree scan
    int t = threadIdx.x, b = blockIdx.x;
    if (t < BNODES) cnt[t] = 0;
    __syncthreads();
    int m = gcur[b];
    const int* p = pairs + (size_t)b * BCAP;
    // pass 1: node degree counts
    for (int i = t; i < m; i += 1024) {
        atomicAdd(&cnt[p[i] >> 17], 1);
    }
    __syncthreads();
    // local inclusive scan over deg (= cnt + 1 self-loop for valid nodes)
    if (t < BNODES) {
        int node = (b << BSHIFT) + t;
        snode[t] = (node < n) ? cnt[t] + 1 : 0;
    }
    __syncthreads();
    for (int off = 1; off < BNODES; off <<= 1) {
        int v = (t < BNODES && t >= off) ? snode[t - off] : 0;
        __syncthreads();
        if (t < BNODES) snode[t] += v;
        __syncthreads();
    }
    int bbase = bucket_base[b];
    if (t < BNODES) {
        int node = (b << BSHIFT) + t;
        if (node < n) {
            int deg = cnt[t] + 1;
            int ex = bbase + snode[t] - deg;    // exclusive position
            row_start[node] = ex;
            dis[node] = rsqrtf((float)deg);
            csr_src[ex] = node;                 // self-loop entry
            cnt[t] = ex + 1;                    // cursor
            if (node == n - 1) row_start[n] = ex + deg;
        }
    }
    __syncthreads();
    // pass 2: fill CSR via LDS cursors (pairs now L2-hot)
    for (int i = t; i < m; i += 1024) {
        int pk = p[i];
        int pos = atomicAdd(&cnt[pk >> 17], 1);
        csr_src[pos] = pk & 0x1FFFF;
    }
}

// ---------------- bf16 MFMA GEMM: H[M x NOUT] = dis[m] * (A[M x 128] * W[128 x NOUT]) ----
// AFP32: A is fp32 (layer 1 reads x directly, converts in-register)
template <int NOUT, bool AFP32>
__global__ __launch_bounds__(256) void gemm_bf16_kernel(const void* __restrict__ Av,
                                                        const unsigned short* __restrict__ Wt,
                                                        const float* __restrict__ dis,
                                                        unsigned short* __restrict__ H, int M) {
    int wave = (blockIdx.x * 256 + threadIdx.x) >> 6;
    int lane = threadIdx.x & 63;
    int m0 = wave << 4;
    if (m0 >= M) return;                  // M divisible by 16
    int m = lane & 15, q = lane >> 4;
    constexpr int NT = NOUT / 16;
    f32x4 acc[NT];
    #pragma unroll
    for (int t = 0; t < NT; t++) acc[t] = (f32x4){0.f, 0.f, 0.f, 0.f};
    const short8* Arow = (const short8*)((const unsigned short*)Av + (size_t)(m0 + m) * 128);
    const float*  Arow32 = (const float*)Av + (size_t)(m0 + m) * 128;
    #pragma unroll
    for (int kk = 0; kk < 4; kk++) {
        short8 a;
        if (AFP32) {
            float4 u = *(const float4*)(Arow32 + kk * 32 + q * 8);
            float4 v = *(const float4*)(Arow32 + kk * 32 + q * 8 + 4);
            a[0] = (short)f2bf(u.x); a[1] = (short)f2bf(u.y);
            a[2] = (short)f2bf(u.z); a[3] = (short)f2bf(u.w);
            a[4] = (short)f2bf(v.x); a[5] = (short)f2bf(v.y);
            a[6] = (short)f2bf(v.z); a[7] = (short)f2bf(v.w);
        } else {
            a = Arow[kk * 4 + q];         // A[m0+m][kk*32 + q*8 .. +7]
        }
        #pragma unroll
        for (int t = 0; t < NT; t++) {
            const short8* Bp = (const short8*)(Wt + (size_t)(t * 16 + m) * 128);
            short8 b = Bp[kk * 4 + q];    // W[kk*32+q*8+j][t*16+m]
            acc[t] = __builtin_amdgcn_mfma_f32_16x16x32_bf16(a, b, acc[t], 0, 0, 0);
        }
    }
    float ds[4];
    #pragma unroll
    for (int r = 0; r < 4; r++) ds[r] = dis[m0 + q * 4 + r];
    #pragma unroll
    for (int t = 0; t < NT; t++)
        #pragma unroll
        for (int r = 0; r < 4; r++)
            H[(size_t)(m0 + q * 4 + r) * NOUT + t * 16 + m] = f2bf(acc[t][r] * ds[r]);
}

// ---------------- FUSED: CSR aggregate (F=128) + relu + next-layer GEMM ----------
// WG = 256 threads = 16 groups x 16 lanes; group g aggregates row (blk*16+g):
//   X[row] = relu(dis[row] * sum Hs + bias)   -> bf16 in LDS [16][128] (XOR-swizzled)
// then 4 waves compute Hout[16 x NOUT] = dis ⊙ (X @ Wt^T-layout) via MFMA.
// Weights + output-dis are prefetched into registers BEFORE the barrier so the
// convoy tail (max-of-16 row degrees) hides their latency; LDS is XOR-swizzled
// (16B granule) so the MFMA A-frag read is conflict-free (was 16-way).
template <int NOUT>
__global__ __launch_bounds__(256) void agg_gemm_kernel(const unsigned short* __restrict__ H,
                                                       const int* __restrict__ row_start,
                                                       const int* __restrict__ csr_src,
                                                       const float* __restrict__ dis,
                                                       const float* __restrict__ bias,
                                                       const unsigned short* __restrict__ Wt,
                                                       unsigned short* __restrict__ Hout,
                                                       int n) {
    __shared__ unsigned short X[16][128];      // 4 KB, swizzled layout
    int t = threadIdx.x;
    int g = t >> 4, gl = t & 15;
    int row = blockIdx.x * 16 + g;
    int c = gl * 8;
    float acc[8];
    #pragma unroll
    for (int i = 0; i < 8; i++) acc[i] = 0.f;
    if (row < n) {
        int p0 = row_start[row], p1 = row_start[row + 1];
        int p = p0;
        for (; p + 8 <= p1; p += 8) {
            int e[8];
            #pragma unroll
            for (int u = 0; u < 8; u++) e[u] = csr_src[p + u];
            uint4 h[8];
            #pragma unroll
            for (int u = 0; u < 8; u++) h[u] = *(const uint4*)(H + (size_t)e[u] * 128 + c);
            #pragma unroll
            for (int u = 0; u < 8; u++) {
                acc[0] += bflo(h[u].x); acc[1] += bfhi(h[u].x);
                acc[2] += bflo(h[u].y); acc[3] += bfhi(h[u].y);
                acc[4] += bflo(h[u].z); acc[5] += bfhi(h[u].z);
                acc[6] += bflo(h[u].w); acc[7] += bfhi(h[u].w);
            }
        }
        for (; p + 4 <= p1; p += 4) {
            int e0 = csr_src[p],     e1 = csr_src[p + 1];
            int e2 = csr_src[p + 2], e3 = csr_src[p + 3];
            uint4 h0 = *(const uint4*)(H + (size_t)e0 * 128 + c);
            uint4 h1 = *(const uint4*)(H + (size_t)e1 * 128 + c);
            uint4 h2 = *(const uint4*)(H + (size_t)e2 * 128 + c);
            uint4 h3 = *(const uint4*)(H + (size_t)e3 * 128 + c);
            acc[0] += bflo(h0.x) + bflo(h1.x) + bflo(h2.x) + bflo(h3.x);
            acc[1] += bfhi(h0.x) + bfhi(h1.x) + bfhi(h2.x) + bfhi(h3.x);
            acc[2] += bflo(h0.y) + bflo(h1.y) + bflo(h2.y) + bflo(h3.y);
            acc[3] += bfhi(h0.y) + bfhi(h1.y) + bfhi(h2.y) + bfhi(h3.y);
            acc[4] += bflo(h0.z) + bflo(h1.z) + bflo(h2.z) + bflo(h3.z);
            acc[5] += bfhi(h0.z) + bfhi(h1.z) + bfhi(h2.z) + bfhi(h3.z);
            acc[6] += bflo(h0.w) + bflo(h1.w) + bflo(h2.w) + bflo(h3.w);
            acc[7] += bfhi(h0.w) + bfhi(h1.w) + bfhi(h2.w) + bfhi(h3.w);
        }
        for (; p < p1; p++) {
            int e = csr_src[p];
            uint4 h = *(const uint4*)(H + (size_t)e * 128 + c);
            acc[0] += bflo(h.x); acc[1] += bfhi(h.x);
            acc[2] += bflo(h.y); acc[3] += bfhi(h.y);
            acc[4] += bflo(h.z); acc[5] += bfhi(h.z);
            acc[6] += bflo(h.w); acc[7] += bfhi(h.w);
        }
        float dd = dis[row];
        #pragma unroll
        for (int i = 0; i < 8; i++)
            acc[i] = fmaxf(acc[i] * dd + bias[c + i], 0.f);
    }
    // --- prefetch GEMM-phase operands BEFORE the barrier (hidden under tail) ---
    int wv = t >> 6, lane = t & 63;
    int m = lane & 15, q = lane >> 4;
    constexpr int TPW = NOUT / 64;             // tiles per wave: 128->2, 64->1
    short8 bfrag[4][TPW];
    #pragma unroll
    for (int kk = 0; kk < 4; kk++)
        #pragma unroll
        for (int tt = 0; tt < TPW; tt++) {
            const short8* Bp = (const short8*)(Wt + (size_t)((wv * TPW + tt) * 16 + m) * 128);
            bfrag[kk][tt] = Bp[kk * 4 + q];
        }
    int obase = blockIdx.x * 16;
    float dsout[4];
    #pragma unroll
    for (int r = 0; r < 4; r++) {
        int rr = obase + q * 4 + r;
        dsout[r] = (rr < n) ? dis[rr] : 0.f;
    }
    // pack to LDS, XOR-swizzled (rows >= n stay zero)
    uint4 pk;
    pk.x = ((unsigned int)f2bf(acc[1]) << 16) | f2bf(acc[0]);
    pk.y = ((unsigned int)f2bf(acc[3]) << 16) | f2bf(acc[2]);
    pk.z = ((unsigned int)f2bf(acc[5]) << 16) | f2bf(acc[4]);
    pk.w = ((unsigned int)f2bf(acc[7]) << 16) | f2bf(acc[6]);
    *(uint4*)&X[g][c ^ ((g & 7) << 3)] = pk;
    __syncthreads();
    // ---- GEMM phase: pure-register B, swizzled LDS A ----
    f32x4 gacc[TPW];
    #pragma unroll
    for (int tt = 0; tt < TPW; tt++) gacc[tt] = (f32x4){0.f, 0.f, 0.f, 0.f};
    #pragma unroll
    for (int kk = 0; kk < 4; kk++) {
        short8 a = *(const short8*)&X[m][(kk * 32 + q * 8) ^ ((m & 7) << 3)];
        #pragma unroll
        for (int tt = 0; tt < TPW; tt++)
            gacc[tt] = __builtin_amdgcn_mfma_f32_16x16x32_bf16(a, bfrag[kk][tt], gacc[tt], 0, 0, 0);
    }
    #pragma unroll
    for (int r = 0; r < 4; r++) {
        int rr = obase + q * 4 + r;
        if (rr < n) {
            #pragma unroll
            for (int tt = 0; tt < TPW; tt++)
                Hout[(size_t)rr * NOUT + (wv * TPW + tt) * 16 + m] = f2bf(gacc[tt][r] * dsout[r]);
        }
    }
}

// ---------------- CSR aggregation (bf16 H pre-scaled by dis[src], 4B edges) ----------
// out[d] = dis[d] * sum_{s in N(d)} Hs[s] + bias   (final layer: F=64, fp32 out)
template <int EPL, bool RELU, bool OUTBF>   // EPL = bf16 features per lane (8 or 4)
__global__ __launch_bounds__(256) void aggregate_kernel(const unsigned short* __restrict__ H,
                                                        const int* __restrict__ row_start,
                                                        const int* __restrict__ csr_src,
                                                        const float* __restrict__ dis,
                                                        const float* __restrict__ bias,
                                                        void* __restrict__ out, int n) {
    constexpr int F = EPL * 16;             // features per row
    int row = (blockIdx.x * 256 + threadIdx.x) >> 4;
    int gl  = threadIdx.x & 15;
    if (row >= n) return;
    int c = gl * EPL;
    float acc[EPL];
    #pragma unroll
    for (int i = 0; i < EPL; i++) acc[i] = 0.f;
    int p0 = row_start[row], p1 = row_start[row + 1];
    int p = p0;
    for (; p + 8 <= p1; p += 8) {
        int e[8];
        #pragma unroll
        for (int u = 0; u < 8; u++) e[u] = csr_src[p + u];
        if (EPL == 8) {
            uint4 h[8];
            #pragma unroll
            for (int u = 0; u < 8; u++) h[u] = *(const uint4*)(H + (size_t)e[u] * F + c);
            #pragma unroll
            for (int u = 0; u < 8; u++) {
                acc[0] += bflo(h[u].x); acc[1] += bfhi(h[u].x);
                acc[2] += bflo(h[u].y); acc[3] += bfhi(h[u].y);
                acc[4] += bflo(h[u].z); acc[5] += bfhi(h[u].z);
                acc[6] += bflo(h[u].w); acc[7] += bfhi(h[u].w);
            }
        } else {
            uint2 h[8];
            #pragma unroll
            for (int u = 0; u < 8; u++) h[u] = *(const uint2*)(H + (size_t)e[u] * F + c);
            #pragma unroll
            for (int u = 0; u < 8; u++) {
                acc[0] += bflo(h[u].x); acc[1] += bfhi(h[u].x);
                acc[2] += bflo(h[u].y); acc[3] += bfhi(h[u].y);
            }
        }
    }
    for (; p + 4 <= p1; p += 4) {
        int e0 = csr_src[p],     e1 = csr_src[p + 1];
        int e2 = csr_src[p + 2], e3 = csr_src[p + 3];
        if (EPL == 8) {
            uint4 h0 = *(const uint4*)(H + (size_t)e0 * F + c);
            uint4 h1 = *(const uint4*)(H + (size_t)e1 * F + c);
            uint4 h2 = *(const uint4*)(H + (size_t)e2 * F + c);
            uint4 h3 = *(const uint4*)(H + (size_t)e3 * F + c);
            acc[0] += bflo(h0.x) + bflo(h1.x) + bflo(h2.x) + bflo(h3.x);
            acc[1] += bfhi(h0.x) + bfhi(h1.x) + bfhi(h2.x) + bfhi(h3.x);
            acc[2] += bflo(h0.y) + bflo(h1.y) + bflo(h2.y) + bflo(h3.y);
            acc[3] += bfhi(h0.y) + bfhi(h1.y) + bfhi(h2.y) + bfhi(h3.y);
            acc[4] += bflo(h0.z) + bflo(h1.z) + bflo(h2.z) + bflo(h3.z);
            acc[5] += bfhi(h0.z) + bfhi(h1.z) + bfhi(h2.z) + bfhi(h3.z);
            acc[6] += bflo(h0.w) + bflo(h1.w) + bflo(h2.w) + bflo(h3.w);
            acc[7] += bfhi(h0.w) + bfhi(h1.w) + bfhi(h2.w) + bfhi(h3.w);
        } else {
            uint2 h0 = *(const uint2*)(H + (size_t)e0 * F + c);
            uint2 h1 = *(const uint2*)(H + (size_t)e1 * F + c);
            uint2 h2 = *(const uint2*)(H + (size_t)e2 * F + c);
            uint2 h3 = *(const uint2*)(H + (size_t)e3 * F + c);
            acc[0] += bflo(h0.x) + bflo(h1.x) + bflo(h2.x) + bflo(h3.x);
            acc[1] += bfhi(h0.x) + bfhi(h1.x) + bfhi(h2.x) + bfhi(h3.x);
            acc[2] += bflo(h0.y) + bflo(h1.y) + bflo(h2.y) + bflo(h3.y);
            acc[3] += bfhi(h0.y) + bfhi(h1.y) + bfhi(h2.y) + bfhi(h3.y);
        }
    }
    for (; p < p1; p++) {
        int e = csr_src[p];
        if (EPL == 8) {
            uint4 h = *(const uint4*)(H + (size_t)e * F + c);
            acc[0] += bflo(h.x); acc[1] += bfhi(h.x);
            acc[2] += bflo(h.y); acc[3] += bfhi(h.y);
            acc[4] += bflo(h.z); acc[5] += bfhi(h.z);
            acc[6] += bflo(h.w); acc[7] += bfhi(h.w);
        } else {
            uint2 h = *(const uint2*)(H + (size_t)e * F + c);
            acc[0] += bflo(h.x); acc[1] += bfhi(h.x);
            acc[2] += bflo(h.y); acc[3] += bfhi(h.y);
        }
    }
    float dd = dis[row];
    #pragma unroll
    for (int i = 0; i < EPL; i++) {
        acc[i] = acc[i] * dd + bias[c + i];
        if (RELU) acc[i] = fmaxf(acc[i], 0.f);
    }
    if (OUTBF) {
        unsigned short* ob = (unsigned short*)out + (size_t)row * F + c;
        if (EPL == 8) {
            uint4 pk;
            pk.x = ((unsigned int)f2bf(acc[1]) << 16) | f2bf(acc[0]);
            pk.y = ((unsigned int)f2bf(acc[3]) << 16) | f2bf(acc[2]);
            pk.z = ((unsigned int)f2bf(acc[5]) << 16) | f2bf(acc[4]);
            pk.w = ((unsigned int)f2bf(acc[7]) << 16) | f2bf(acc[6]);
            *(uint4*)ob = pk;
        } else {
            uint2 pk;
            pk.x = ((unsigned int)f2bf(acc[1]) << 16) | f2bf(acc[0]);
            pk.y = ((unsigned int)f2bf(acc[3]) << 16) | f2bf(acc[2]);
            *(uint2*)ob = pk;
        }
    } else {
        float* of = (float*)out + (size_t)row * F + c;
        #pragma unroll
        for (int i = 0; i < EPL; i += 4) {
            *(float4*)(of + i) = make_float4(acc[i], acc[i + 1], acc[i + 2], acc[i + 3]);
        }
    }
}

// ---------------- decode: hidden = z[a]*z[b]; logits = sum; normalize ----------------
// One 16-lane group per TWO pairs: 4 float4 gathers in flight per group.
__global__ __launch_bounds__(256) void decode_kernel(const float* __restrict__ Z,
                                                     const int* __restrict__ eli, int EL,
                                                     float* __restrict__ out_h,
                                                     float* __restrict__ out_l) {
    int g  = (blockIdx.x * 256 + threadIdx.x) >> 4;
    int gl = threadIdx.x & 15;
    int q0 = g * 2;
    if (q0 >= EL) return;
    int q1 = q0 + 1;
    bool has1 = q1 < EL;
    int a0 = eli[q0], b0 = eli[EL + q0];
    int a1 = has1 ? eli[q1] : a0;
    int b1 = has1 ? eli[EL + q1] : b0;
    float4 za0 = *(const float4*)(Z + (size_t)a0 * 64 + gl * 4);
    float4 zb0 = *(const float4*)(Z + (size_t)b0 * 64 + gl * 4);
    float4 za1 = *(const float4*)(Z + (size_t)a1 * 64 + gl * 4);
    float4 zb1 = *(const float4*)(Z + (size_t)b1 * 64 + gl * 4);

    float h00 = za0.x * zb0.x, h01 = za0.y * zb0.y, h02 = za0.z * zb0.z, h03 = za0.w * zb0.w;
    float h10 = za1.x * zb1.x, h11 = za1.y * zb1.y, h12 = za1.z * zb1.z, h13 = za1.w * zb1.w;
    float s0  = h00 + h01 + h02 + h03;
    float ss0 = h00 * h00 + h01 * h01 + h02 * h02 + h03 * h03;
    float s1  = h10 + h11 + h12 + h13;
    float ss1 = h10 * h10 + h11 * h11 + h12 * h12 + h13 * h13;
    #pragma unroll
    for (int off = 8; off > 0; off >>= 1) {
        s0  += __shfl_xor(s0, off, 64);
        ss0 += __shfl_xor(ss0, off, 64);
        s1  += __shfl_xor(s1, off, 64);
        ss1 += __shfl_xor(ss1, off, 64);
    }
    float inv0 = 1.0f / fmaxf(sqrtf(ss0), 1e-12f);
    *(float4*)(out_h + (size_t)q0 * 64 + gl * 4) =
        make_float4(h00 * inv0, h01 * inv0, h02 * inv0, h03 * inv0);
    if (gl == 0) out_l[q0] = s0;
    if (has1) {
        float inv1 = 1.0f / fmaxf(sqrtf(ss1), 1e-12f);
        *(float4*)(out_h + (size_t)q1 * 64 + gl * 4) =
            make_float4(h10 * inv1, h11 * inv1, h12 * inv1, h13 * inv1);
        if (gl == 0) out_l[q1] = s1;
    }
}

extern "C" void kernel_launch(void* const* d_in, const int* in_sizes, int n_in,
                              void* d_out, int out_size, void* d_ws, size_t ws_size,
                              hipStream_t stream) {
    const float* x  = (const float*)d_in[0];
    const float* W1 = (const float*)d_in[1];
    const float* b1 = (const float*)d_in[2];
    const float* W2 = (const float*)d_in[3];
    const float* b2 = (const float*)d_in[4];
    const float* W3 = (const float*)d_in[5];
    const float* b3 = (const float*)d_in[6];
    const int* edge_index = (const int*)d_in[7];
    const int* eli        = (const int*)d_in[8];

    const int N  = in_sizes[0] / DIN;
    const int E  = in_sizes[7] / 2;
    const int EL = in_sizes[8] / 2;
    const int NBUCK = (N + BNODES - 1) >> BSHIFT;   // 196 for N=100000 (<=256 required)

    char* w = (char*)d_ws;
    auto alloc = [&](size_t bytes) -> char* {
        char* p = w; w += (bytes + 255) & ~(size_t)255; return p;
    };
    unsigned short* bufA  = (unsigned short*)alloc((size_t)N * DH * 2);  // H1 then H3 (bf16)
    unsigned short* bufB  = (unsigned short*)alloc((size_t)N * DH * 2);  // H2 (bf16)
    float*          Z3    = (float*)alloc((size_t)N * DOUT * 4);         // fp32 final embeddings
    unsigned short* Wt1   = (unsigned short*)alloc(128 * 128 * 2);
    unsigned short* Wt2   = (unsigned short*)alloc(128 * 128 * 2);
    unsigned short* Wt3   = (unsigned short*)alloc(64 * 128 * 2);
    int*            row_start = (int*)alloc((size_t)(N + 1) * 4);
    float*          dis    = (float*)alloc((size_t)N * 4);
    int*            gcur   = (int*)alloc(256 * 4);                       // bucket counts
    int*            bucket_base = (int*)alloc(256 * 4);                  // bucket CSR bases
    int*            csr_src = (int*)alloc((size_t)(E + N) * 4);
    int*            pairs  = (int*)alloc((size_t)NBUCK * BCAP * 4);      // bucketed edges

    float* out_h = (float*)d_out;
    float* out_l = out_h + (size_t)EL * DOUT;

    // --- build CSR (bucketed multisplit, consolidated) ---
    prep_w_kernel<<<64, 256, 0, stream>>>(W1, W2, W3, Wt1, Wt2, Wt3, gcur);
    bin_scatter_kernel<<<(E + CHUNK - 1) / CHUNK, 256, 0, stream>>>(edge_index, E, gcur, pairs);
    scan_buckets_kernel<<<1, 256, 0, stream>>>(gcur, bucket_base, NBUCK, N);
    bucket_build_kernel<<<NBUCK, 1024, 0, stream>>>(pairs, gcur, bucket_base,
                                                    row_start, dis, csr_src, N);

    const int gemm_grid = ((N / 16) * 64 + 255) / 256;
    const int fuse_grid = (N + 15) / 16;             // 16 rows per WG
    const int agg_grid  = (N * 16 + 255) / 256;      // 16 lanes per row

    // --- layer 1 GEMM (reads fp32 x directly) ---
    gemm_bf16_kernel<128, true><<<gemm_grid, 256, 0, stream>>>(x, Wt1, dis, bufA, N);
    // --- aggregate1 + relu + GEMM2 (fused) ---
    agg_gemm_kernel<128><<<fuse_grid, 256, 0, stream>>>(bufA, row_start, csr_src, dis, b1, Wt2, bufB, N);
    // --- aggregate2 + relu + GEMM3 (fused) ---
    agg_gemm_kernel<64><<<fuse_grid, 256, 0, stream>>>(bufB, row_start, csr_src, dis, b2, Wt3, bufA, N);
    // --- aggregate3 (final, fp32 out) ---
    aggregate_kernel<4, false, false><<<agg_grid, 256, 0, stream>>>(bufA, row_start, csr_src, dis, b3, Z3, N);
    // --- decode ---
    const int dec_groups = (EL + 1) / 2;
    decode_kernel<<<(dec_groups * 16 + 255) / 256, 256, 0, stream>>>(Z3, eli, EL, out_h, out_l);
}